// Round 6
// baseline (307.853 us; speedup 1.0000x reference)
//
#include <hip/hip_runtime.h>

#define N_NODES 100000
#define N_EDGES 1600000
#define IN_F    256
#define OUT_F   128

#define BROWS2   256                  // rows per bucket
#define NB2      391                  // ceil(N_NODES / 256)
#define CAPB     4800                 // slots/bucket (mean 4096, sigma 64 -> +11 sigma)
#define PART_EPB 2048                 // edges per partition block
#define NPART    782                  // ceil(N_EDGES / PART_EPB); 782*2048 >= 1.6M
#define KE       (PART_EPB / 256)     // 8 edges/thread in partition role
#define NGEMM    1563                 // ceil(N_NODES / 64) gemm tile blocks
#define KB       ((CAPB + 511) / 512) // 10 edges/thread in bucket_build (512 thr)

typedef __attribute__((ext_vector_type(8))) short   s16x8;   // 8 x bf16 (MFMA A/B frag)
typedef __attribute__((ext_vector_type(4))) float   f32x4;   // MFMA C/D frag
typedef __attribute__((ext_vector_type(8))) unsigned short u16x8;

__device__ __forceinline__ unsigned short f2bf(float f) {   // fp32 -> bf16 RNE
    unsigned u = __float_as_uint(f);
    u += 0x7FFFu + ((u >> 16) & 1u);
    return (unsigned short)(u >> 16);
}
__device__ __forceinline__ float bf2f(unsigned short h) {
    return __uint_as_float((unsigned)h << 16);
}

// ---------------------------------------------------------------------------
// K0: Wt[n][k] = bf16(W[k][n])  + zero bucket cursors
// ---------------------------------------------------------------------------
__global__ __launch_bounds__(256) void wt_build(const float* __restrict__ W,
                                                unsigned short* __restrict__ Wt,
                                                int* __restrict__ cursorA) {
    const int n = blockIdx.x;       // 0..127
    const int k = threadIdx.x;      // 0..255
    Wt[n * IN_F + k] = f2bf(W[(size_t)k * OUT_F + n]);
    const int idx = blockIdx.x * 256 + threadIdx.x;
    if (idx < NB2) cursorA[idx] = 0;
}

// ---------------------------------------------------------------------------
// K1: FUSED gemm + partition (block-role split; disjoint in/out, no race).
// Blocks 0..NPART-1: partition edges into 391 coarse buckets (r5's kernel,
//   KE=8). Placed FIRST so their memory/atomic latency hides under the gemm
//   blocks' compute. Fusion deletes a launch boundary (~10-20us gap) and
//   overlaps partition (~20us) behind gemm.
// Blocks NPART..: 64x128 MFMA tile of support = bf16(X @ W).
// ---------------------------------------------------------------------------
__global__ __launch_bounds__(256) void fused_gp(const float* __restrict__ X,
                                                const unsigned short* __restrict__ Wt,
                                                unsigned short* __restrict__ support,
                                                const int* __restrict__ arow,
                                                const int* __restrict__ acol,
                                                const float* __restrict__ aval,
                                                int* __restrict__ cursorA,
                                                int2* __restrict__ epackA) {
    __shared__ union {
        struct {
            unsigned short As[64][40];   // [m][k], 80B rows
            unsigned short Bs[128][40];  // [n][k]
            unsigned short Ct[64][136];  // epilogue repack
        } g;                             // 33 KB (gemm role)
        struct {
            int cnt[NB2];
            int basep[NB2];
        } p;                             // 3.1 KB (partition role)
    } sm;

    const int t = threadIdx.x;

    if (blockIdx.x < NPART) {
        // ------------------ partition role ------------------
        for (int k = t; k < NB2; k += 256) sm.p.cnt[k] = 0;
        __syncthreads();

        const int base = blockIdx.x * PART_EPB;
        int pk_[KE], vv_[KE], b_[KE], rk_[KE];
#pragma unroll
        for (int k = 0; k < KE; ++k) {
            const int i = base + t + k * 256;
            b_[k] = -1;
            if (i < N_EDGES) {
                const int r = arow[i];
                b_[k]  = r >> 8;
                pk_[k] = ((r & (BROWS2 - 1)) << 17) | acol[i];
                vv_[k] = __float_as_int(aval[i]);
                rk_[k] = atomicAdd(&sm.p.cnt[b_[k]], 1);       // LDS, 1/edge
            }
        }
        __syncthreads();
        for (int k = t; k < NB2; k += 256) {
            const int c = sm.p.cnt[k];
            if (c > 0) sm.p.basep[k] = atomicAdd(&cursorA[k], c);
        }
        __syncthreads();
#pragma unroll
        for (int k = 0; k < KE; ++k) {
            if (b_[k] >= 0) {
                const int pos = sm.p.basep[b_[k]] + rk_[k];
                if (pos < CAPB)      // 11-sigma guard
                    epackA[(size_t)b_[k] * CAPB + pos] = make_int2(pk_[k], vv_[k]);
            }
        }
        return;
    }

    // ------------------ gemm role ------------------
    const int wid  = t >> 6;
    const int lane = t & 63;
    const int tm   = lane & 15;
    const int quad = lane >> 4;
    const int row0 = (blockIdx.x - NPART) * 64;

    f32x4 acc[8];
#pragma unroll
    for (int c = 0; c < 8; ++c) acc[c] = (f32x4){0.f, 0.f, 0.f, 0.f};

    for (int kb = 0; kb < IN_F; kb += 32) {
        // stage A: 64 rows x 32 k fp32 -> bf16. thread: m=t>>2, k0=(t&3)*8
        {
            const int m  = t >> 2;
            const int k0 = (t & 3) * 8;
            const int gr = row0 + m;
            float4 x0 = make_float4(0.f, 0.f, 0.f, 0.f), x1 = x0;
            if (gr < N_NODES) {
                const float* xp = &X[(size_t)gr * IN_F + kb + k0];
                x0 = *(const float4*)xp;
                x1 = *(const float4*)(xp + 4);
            }
            ushort4 a0, a1;
            a0.x = f2bf(x0.x); a0.y = f2bf(x0.y); a0.z = f2bf(x0.z); a0.w = f2bf(x0.w);
            a1.x = f2bf(x1.x); a1.y = f2bf(x1.y); a1.z = f2bf(x1.z); a1.w = f2bf(x1.w);
            *(ushort4*)&sm.g.As[m][k0]     = a0;
            *(ushort4*)&sm.g.As[m][k0 + 4] = a1;
        }
        // stage B: 128 n x 32 k bf16 from Wt (two u16x8 writes = 16 shorts)
        {
            const int n  = t >> 1;
            const int k0 = (t & 1) * 16;
            const unsigned short* wp = &Wt[(size_t)n * IN_F + kb + k0];
            *(u16x8*)&sm.g.Bs[n][k0]     = *(const u16x8*)wp;
            *(u16x8*)&sm.g.Bs[n][k0 + 8] = *(const u16x8*)(wp + 8);
        }
        __syncthreads();

        const s16x8 a = *(const s16x8*)&sm.g.As[wid * 16 + tm][quad * 8];
#pragma unroll
        for (int c = 0; c < 8; ++c) {
            const s16x8 b = *(const s16x8*)&sm.g.Bs[c * 16 + tm][quad * 8];
            acc[c] = __builtin_amdgcn_mfma_f32_16x16x32_bf16(a, b, acc[c], 0, 0, 0);
        }
        __syncthreads();
    }

    // epilogue: regs -> LDS (bf16) -> coalesced global
#pragma unroll
    for (int c = 0; c < 8; ++c) {
        const int col = c * 16 + tm;
#pragma unroll
        for (int reg = 0; reg < 4; ++reg) {
            const int m = wid * 16 + quad * 4 + reg;
            sm.g.Ct[m][col] = f2bf(acc[c][reg]);
        }
    }
    __syncthreads();
    {
        const int m   = t >> 2;
        const int seg = (t & 3) * 32;
        const int gr  = row0 + m;
        if (gr < N_NODES) {
            unsigned short* op = &support[(size_t)gr * OUT_F + seg];
#pragma unroll
            for (int i = 0; i < 4; ++i)
                *(u16x8*)(op + i * 8) = *(const u16x8*)&sm.g.Ct[m][seg + i * 8];
        }
    }
}

// ---------------------------------------------------------------------------
// K2: per-bucket exact CSR build — now 512 threads (391-block grid was 1.5
// blocks/CU at 4 waves = latency-starved; 8 waves/block doubles hiding, and
// KB drops 19->10 so the register arrays shrink).
// ---------------------------------------------------------------------------
__global__ __launch_bounds__(512) void bucket_build(const int* __restrict__ cursorA,
                                                    const int2* __restrict__ epackA,
                                                    int2* __restrict__ rowmeta,
                                                    int2* __restrict__ epackB) {
    __shared__ int cnt[BROWS2];
    __shared__ int excl[BROWS2];
    __shared__ int wsum[4];
    const int b = blockIdx.x;
    const int t = threadIdx.x;
    if (t < BROWS2) cnt[t] = 0;
    __syncthreads();

    const size_t sa = (size_t)b * CAPB;
    const int n = min(cursorA[b], CAPB);

    int pk_[KB], vv_[KB], rk_[KB];
#pragma unroll
    for (int k = 0; k < KB; ++k) {
        const int i = t + k * 512;
        rk_[k] = -1;
        if (i < n) {
            const int2 e = epackA[sa + i];
            pk_[k] = e.x;
            vv_[k] = e.y;
            rk_[k] = atomicAdd(&cnt[e.x >> 17], 1);   // LDS, 1 per edge
        }
    }
    __syncthreads();

    // exclusive scan of cnt[256] by threads 0..255 (all threads hit barriers)
    int x = 0, my = 0;
    if (t < BROWS2) {
        const int lane = t & 63;
        my = cnt[t];
        x  = my;
#pragma unroll
        for (int off = 1; off < 64; off <<= 1) {
            const int y = __shfl_up(x, off, 64);
            if (lane >= off) x += y;
        }
        if (lane == 63) wsum[t >> 6] = x;
    }
    __syncthreads();
    if (t < BROWS2) {
        int pre = x - my;
        const int w = t >> 6;
        for (int kk = 0; kk < w; ++kk) pre += wsum[kk];
        excl[t] = pre;
        const int r = b * BROWS2 + t;
        if (r < N_NODES) rowmeta[r] = make_int2((int)sa + pre, my);
    }
    __syncthreads();

#pragma unroll
    for (int k = 0; k < KB; ++k) {
        if (rk_[k] >= 0) {
            const int rl  = pk_[k] >> 17;
            const int pos = excl[rl] + rk_[k];
            epackB[sa + pos] = make_int2(pk_[k] & 0x1FFFF, vv_[k]);
        }
    }
}

// ---------------------------------------------------------------------------
// K3: CSR gather — 32 lanes/row, lane owns 4 feats; 8-edge ILP main tier
// (16 outstanding loads/group vs 8) + 4-edge + scalar tails.
// ---------------------------------------------------------------------------
__global__ __launch_bounds__(256) void csr_gather(const int2* __restrict__ rowmeta,
                                                  const int2* __restrict__ epackB,
                                                  const unsigned short* __restrict__ support,
                                                  const float* __restrict__ bias,
                                                  float* __restrict__ out) {
    const int t = threadIdx.x;
    const int g = t >> 5;
    const int l = t & 31;
    const int r = blockIdx.x * 8 + g;
    if (r >= N_NODES) return;

    const int2 rm   = rowmeta[r];
    const int start = rm.x;
    const int deg   = rm.y;

    float4 acc = *(const float4*)&bias[l * 4];

    int i = 0;
    for (; i + 8 <= deg; i += 8) {
        const int2 e0 = epackB[start + i + 0];
        const int2 e1 = epackB[start + i + 1];
        const int2 e2 = epackB[start + i + 2];
        const int2 e3 = epackB[start + i + 3];
        const int2 e4 = epackB[start + i + 4];
        const int2 e5 = epackB[start + i + 5];
        const int2 e6 = epackB[start + i + 6];
        const int2 e7 = epackB[start + i + 7];
        const ushort4 u0 = *(const ushort4*)&support[(size_t)e0.x * OUT_F + l * 4];
        const ushort4 u1 = *(const ushort4*)&support[(size_t)e1.x * OUT_F + l * 4];
        const ushort4 u2 = *(const ushort4*)&support[(size_t)e2.x * OUT_F + l * 4];
        const ushort4 u3 = *(const ushort4*)&support[(size_t)e3.x * OUT_F + l * 4];
        const ushort4 u4 = *(const ushort4*)&support[(size_t)e4.x * OUT_F + l * 4];
        const ushort4 u5 = *(const ushort4*)&support[(size_t)e5.x * OUT_F + l * 4];
        const ushort4 u6 = *(const ushort4*)&support[(size_t)e6.x * OUT_F + l * 4];
        const ushort4 u7 = *(const ushort4*)&support[(size_t)e7.x * OUT_F + l * 4];
        const float v0 = __int_as_float(e0.y), v1 = __int_as_float(e1.y);
        const float v2 = __int_as_float(e2.y), v3 = __int_as_float(e3.y);
        const float v4 = __int_as_float(e4.y), v5 = __int_as_float(e5.y);
        const float v6 = __int_as_float(e6.y), v7 = __int_as_float(e7.y);
        acc.x = fmaf(v0, bf2f(u0.x), fmaf(v1, bf2f(u1.x), fmaf(v2, bf2f(u2.x), fmaf(v3, bf2f(u3.x), acc.x))));
        acc.y = fmaf(v0, bf2f(u0.y), fmaf(v1, bf2f(u1.y), fmaf(v2, bf2f(u2.y), fmaf(v3, bf2f(u3.y), acc.y))));
        acc.z = fmaf(v0, bf2f(u0.z), fmaf(v1, bf2f(u1.z), fmaf(v2, bf2f(u2.z), fmaf(v3, bf2f(u3.z), acc.z))));
        acc.w = fmaf(v0, bf2f(u0.w), fmaf(v1, bf2f(u1.w), fmaf(v2, bf2f(u2.w), fmaf(v3, bf2f(u3.w), acc.w))));
        acc.x = fmaf(v4, bf2f(u4.x), fmaf(v5, bf2f(u5.x), fmaf(v6, bf2f(u6.x), fmaf(v7, bf2f(u7.x), acc.x))));
        acc.y = fmaf(v4, bf2f(u4.y), fmaf(v5, bf2f(u5.y), fmaf(v6, bf2f(u6.y), fmaf(v7, bf2f(u7.y), acc.y))));
        acc.z = fmaf(v4, bf2f(u4.z), fmaf(v5, bf2f(u5.z), fmaf(v6, bf2f(u6.z), fmaf(v7, bf2f(u7.z), acc.z))));
        acc.w = fmaf(v4, bf2f(u4.w), fmaf(v5, bf2f(u5.w), fmaf(v6, bf2f(u6.w), fmaf(v7, bf2f(u7.w), acc.w))));
    }
    for (; i + 4 <= deg; i += 4) {
        const int2 e0 = epackB[start + i + 0];
        const int2 e1 = epackB[start + i + 1];
        const int2 e2 = epackB[start + i + 2];
        const int2 e3 = epackB[start + i + 3];
        const ushort4 u0 = *(const ushort4*)&support[(size_t)e0.x * OUT_F + l * 4];
        const ushort4 u1 = *(const ushort4*)&support[(size_t)e1.x * OUT_F + l * 4];
        const ushort4 u2 = *(const ushort4*)&support[(size_t)e2.x * OUT_F + l * 4];
        const ushort4 u3 = *(const ushort4*)&support[(size_t)e3.x * OUT_F + l * 4];
        const float v0 = __int_as_float(e0.y), v1 = __int_as_float(e1.y);
        const float v2 = __int_as_float(e2.y), v3 = __int_as_float(e3.y);
        acc.x = fmaf(v0, bf2f(u0.x), fmaf(v1, bf2f(u1.x), fmaf(v2, bf2f(u2.x), fmaf(v3, bf2f(u3.x), acc.x))));
        acc.y = fmaf(v0, bf2f(u0.y), fmaf(v1, bf2f(u1.y), fmaf(v2, bf2f(u2.y), fmaf(v3, bf2f(u3.y), acc.y))));
        acc.z = fmaf(v0, bf2f(u0.z), fmaf(v1, bf2f(u1.z), fmaf(v2, bf2f(u2.z), fmaf(v3, bf2f(u3.z), acc.z))));
        acc.w = fmaf(v0, bf2f(u0.w), fmaf(v1, bf2f(u1.w), fmaf(v2, bf2f(u2.w), fmaf(v3, bf2f(u3.w), acc.w))));
    }
    for (; i < deg; ++i) {
        const int2 e = epackB[start + i];
        const ushort4 u = *(const ushort4*)&support[(size_t)e.x * OUT_F + l * 4];
        const float v = __int_as_float(e.y);
        acc.x = fmaf(v, bf2f(u.x), acc.x);
        acc.y = fmaf(v, bf2f(u.y), acc.y);
        acc.z = fmaf(v, bf2f(u.z), acc.z);
        acc.w = fmaf(v, bf2f(u.w), acc.w);
    }

    *(float4*)&out[(size_t)r * OUT_F + l * 4] = acc;
}

// ---------------------------------------------------------------------------
extern "C" void kernel_launch(void* const* d_in, const int* in_sizes, int n_in,
                              void* d_out, int out_size, void* d_ws, size_t ws_size,
                              hipStream_t stream) {
    const float* X    = (const float*)d_in[0];
    const int*   arow = (const int*)d_in[1];
    const int*   acol = (const int*)d_in[2];
    const float* aval = (const float*)d_in[3];
    const float* W    = (const float*)d_in[4];
    const float* bias = (const float*)d_in[5];
    float*       out  = (float*)d_out;

    // ws: support bf16 25.6MB | Wt 64KB | rowmeta int2[N] 800KB | cursorA 1.6KB
    //     | epackB int2[NB2*CAPB] 15.0MB        total ~41.5MB
    // epackA (15.0MB) lives in d_out (51.2MB): consumed by bucket_build before
    // csr_gather rewrites out.
    char* ws = (char*)d_ws;
    unsigned short* support = (unsigned short*)ws;  ws += (size_t)N_NODES * OUT_F * 2;
    unsigned short* Wt = (unsigned short*)ws;       ws += (size_t)IN_F * OUT_F * 2;
    int2* rowmeta = (int2*)ws;                      ws += (size_t)N_NODES * 8;
    int*  cursorA = (int*)ws;                       ws += ((NB2 + 7) & ~7) * 4;
    int2* epackB  = (int2*)ws;
    int2* epackA  = (int2*)d_out;

    wt_build<<<OUT_F, 256, 0, stream>>>(W, Wt, cursorA);
    fused_gp<<<NPART + NGEMM, 256, 0, stream>>>(X, Wt, support,
                                                arow, acol, aval, cursorA, epackA);
    bucket_build<<<NB2, 512, 0, stream>>>(cursorA, epackA, rowmeta, epackB);
    csr_gather<<<(N_NODES + 7) / 8, 256, 0, stream>>>(
        rowmeta, epackB, support, bias, out);
}